// Round 8
// baseline (187.742 us; speedup 1.0000x reference)
//
#include <hip/hip_runtime.h>
#include <hip/hip_bf16.h>
#include <stdint.h>

#define HEADS 8
#define DHEAD 64
#define BATCH 4
#define SEQ   8192
#define DIM   256
#define INNER 512
#define QKVC  1536
#define ROWS  32768   // BATCH*SEQ
#define EPS   1e-5f

typedef unsigned short u16;
typedef unsigned long long u64;
typedef __attribute__((ext_vector_type(8))) short bf16x8;
typedef __attribute__((ext_vector_type(4))) float f32x4;

#define AS1 __attribute__((address_space(1)))
#define AS3 __attribute__((address_space(3)))

__device__ __forceinline__ void async16(const void* g, void* l) {
  __builtin_amdgcn_global_load_lds((AS1 unsigned int*)g, (AS3 unsigned int*)l, 16, 0, 0);
}

__device__ __forceinline__ float bf2f(u16 u) {
  union { uint32_t i; float f; } v; v.i = ((uint32_t)u) << 16; return v.f;
}
__device__ __forceinline__ u16 f2bf(float f) {
  union { float f; uint32_t i; } v; v.f = f;
  uint32_t x = v.i;
  return (u16)((x + 0x7fffu + ((x >> 16) & 1u)) >> 16);  // RNE
}

// ---------------- prep (unchanged from R7) ----------------
__global__ __launch_bounds__(256) void prep(const float* __restrict__ x,
                                            const float* __restrict__ w,
                                            u16* __restrict__ xb,
                                            u16* __restrict__ wqB,
                                            u16* __restrict__ wkvP,
                                            float* __restrict__ dots) {
  int bid = blockIdx.x;
  if (bid < 8192) {
    int i = (bid * 256 + threadIdx.x) * 4;
    float4 v = *(const float4*)(x + i);
    ushort4 o; o.x = f2bf(v.x); o.y = f2bf(v.y); o.z = f2bf(v.z); o.w = f2bf(v.w);
    *(ushort4*)(xb + i) = o;
  } else if (bid < 8704) {
    int id = (bid - 8192) * 256 + threadIdx.x;
    int k = id >> 9, j = id & 511;
    wqB[id] = f2bf(w[k * QKVC + j]);            // Wq row-major [256 k][512 j]
  } else if (bid < 9728) {
    int id = (bid - 8704) * 256 + threadIdx.x;  // 0..262143
    int j    = id & 7;
    int lane = (id >> 3) & 63;
    int frag = (id >> 9) & 63;                  // 64 fragments
    int h    = id >> 15;                        // 8 heads
    int fn   = frag & 3;
    int half = (frag >> 2) & 1;
    int ks   = (frag >> 3) & 1;
    int kk   = frag >> 4;
    int col  = half * 64 + fn * 16 + (lane & 15);
    int kidx = kk * 64 + ks * 32 + (lane >> 4) * 8 + j;
    int oc   = (col < 64) ? (512 + h * 64 + col) : (1024 + h * 64 + (col - 64));
    wkvP[id] = f2bf(w[kidx * QKVC + oc]);
  } else {
    int i = ((bid - 9728) * 256 + threadIdx.x) * 4;
    float4 z; z.x = 0.f; z.y = 0.f; z.z = 0.f; z.w = 0.f;
    *(float4*)(dots + i) = z;
  }
}

// ---------------- gemm_tile (R7, used by make_G only) ----------------
__device__ __forceinline__ void gemm_tile(const u16* __restrict__ A, int lda,
                                          const u16* __restrict__ Bt, int ldb,
                                          int K, int row0, int col0,
                                          u16* sA, u16* sB, f32x4 acc[4][4]) {
  const int tid = threadIdx.x, lane = tid & 63, wave = tid >> 6;
  const int m = lane & 15, q = lane >> 4;
  const int mr = (wave >> 1) * 64, nc = (wave & 1) * 64;
  for (int kk = 0; kk < K; kk += 64) {
#pragma unroll
    for (int it = 0; it < 4; ++it) {
      int c = it * 256 + tid;
      int r = c >> 3, kc = (c ^ r) & 7;
      async16(A + (size_t)(row0 + r) * lda + kk + kc * 8, sA + (it * 256 + wave * 64) * 8);
      async16(Bt + (size_t)(col0 + r) * ldb + kk + kc * 8, sB + (it * 256 + wave * 64) * 8);
    }
    __syncthreads();
#pragma unroll
    for (int ks = 0; ks < 2; ++ks) {
      bf16x8 af[4], bfr[4];
#pragma unroll
      for (int f = 0; f < 4; ++f) {
        int ra = mr + f * 16 + m;
        int rb = nc + f * 16 + m;
        af[f]  = *(const bf16x8*)&sA[ra * 64 + (((ks * 4 + q) ^ (m & 7)) * 8)];
        bfr[f] = *(const bf16x8*)&sB[rb * 64 + (((ks * 4 + q) ^ (m & 7)) * 8)];
      }
#pragma unroll
      for (int fm = 0; fm < 4; ++fm)
#pragma unroll
        for (int fn = 0; fn < 4; ++fn)
          acc[fm][fn] = __builtin_amdgcn_mfma_f32_16x16x32_bf16(af[fm], bfr[fn], acc[fm][fn], 0, 0, 0);
    }
    __syncthreads();
  }
}

// ---------------- GEMM-KV (2 heads/block) + instance norm + dots ----------------
// grid (256 row-tiles, 4 head-pairs), 256 thr. Full-K A staged once (64 KB, 1
// drain barrier); each (kk,ks): 4 A-frag ds_reads feed BOTH heads' 32 MFMAs.
// B register-resident from packed weights. Norm mats alias sA post-MFMA,
// XOR-swizzled at 16B granularity (conflict-free). 3 barriers total.
__global__ __launch_bounds__(256, 2) void gemm_kv_dots(const u16* __restrict__ A,
                                                       const u16* __restrict__ wkvP,
                                                       float* __restrict__ dots) {
  __shared__ alignas(16) u16 smem[32768];  // 64 KB: sA[128][256] sw / 4 norm mats
  const int tid = threadIdx.x, lane = tid & 63, wave = tid >> 6;
  const int m = lane & 15, q = lane >> 4;
  const int row0 = blockIdx.x * 128;
  const int hp = blockIdx.y;               // head pair: heads 2hp, 2hp+1
  const int half = wave & 1;               // 0 = k cols, 1 = v cols
  const int rowbase = (wave >> 1) * 64;
  const u16* bpA = wkvP + (size_t)(2 * hp) * 32768 + lane * 8;
  const u16* bpB = wkvP + (size_t)(2 * hp + 1) * 32768 + lane * 8;

  // stage full 128x256 A tile, 16B-chunk XOR swizzle: slot c holds (r=c>>5, kc=(c^r)&31)
#pragma unroll
  for (int it = 0; it < 16; ++it) {
    int c = it * 256 + tid;
    int r = c >> 5, kc = (c ^ r) & 31;
    async16(A + (size_t)(row0 + r) * DIM + kc * 8, smem + c * 8);
  }

  f32x4 acc[4][8];  // [fm][h2*4+fn]
#pragma unroll
  for (int i = 0; i < 4; ++i)
#pragma unroll
    for (int j = 0; j < 8; ++j) acc[i][j] = (f32x4){0.f, 0.f, 0.f, 0.f};

  __syncthreads();  // single staging drain

  for (int kk = 0; kk < 4; ++kk) {
#pragma unroll
    for (int ks = 0; ks < 2; ++ks) {
      int fb = ((kk * 2 + ks) * 2 + half) * 4;
      bf16x8 bra[4], brb[4];
#pragma unroll
      for (int fn = 0; fn < 4; ++fn) {
        bra[fn] = *(const bf16x8*)(bpA + (size_t)(fb + fn) * 512);
        brb[fn] = *(const bf16x8*)(bpB + (size_t)(fb + fn) * 512);
      }
      bf16x8 af[4];
      int g = kk * 8 + ks * 4 + q;
#pragma unroll
      for (int f = 0; f < 4; ++f) {
        int ra = rowbase + f * 16 + m;
        af[f] = *(const bf16x8*)&smem[ra * 256 + ((g ^ (ra & 31)) * 8)];
      }
#pragma unroll
      for (int fm = 0; fm < 4; ++fm)
#pragma unroll
        for (int fn = 0; fn < 4; ++fn) {
          acc[fm][fn]     = __builtin_amdgcn_mfma_f32_16x16x32_bf16(af[fm], bra[fn], acc[fm][fn], 0, 0, 0);
          acc[fm][4 + fn] = __builtin_amdgcn_mfma_f32_16x16x32_bf16(af[fm], brb[fn], acc[fm][4 + fn], 0, 0, 0);
        }
    }
  }
  __syncthreads();  // all sA frag reads done -> safe to alias norm mats

  // norm mats in smem: kn0@0, vn0@8192, kn1@16384, vn1@24576 (u16), each [64 d][128 tok]
  // u64-packed writes, XOR swizzle on 16B chunks: slot8 = ((c8>>1)^(d&15))*2 + (c8&1)
#pragma unroll
  for (int h2 = 0; h2 < 2; ++h2) {
    u16* matb = smem + h2 * 16384 + (half ? 8192 : 0);
#pragma unroll
    for (int fm = 0; fm < 4; ++fm) {
      f32x4 s  = acc[fm][h2 * 4 + 0] + acc[fm][h2 * 4 + 1] + acc[fm][h2 * 4 + 2] + acc[fm][h2 * 4 + 3];
      f32x4 s2 = (f32x4){0.f, 0.f, 0.f, 0.f};
#pragma unroll
      for (int fn = 0; fn < 4; ++fn)
#pragma unroll
        for (int r = 0; r < 4; ++r) {
          float a = acc[fm][h2 * 4 + fn][r];
          s2[r] = fmaf(a, a, s2[r]);
        }
#pragma unroll
      for (int mask = 1; mask <= 8; mask <<= 1) {
#pragma unroll
        for (int r = 0; r < 4; ++r) {
          s[r]  += __shfl_xor(s[r],  mask, 64);
          s2[r] += __shfl_xor(s2[r], mask, 64);
        }
      }
      f32x4 mu, rs;
#pragma unroll
      for (int r = 0; r < 4; ++r) {
        mu[r] = s[r] * (1.f / 64.f);
        float var = s2[r] * (1.f / 64.f) - mu[r] * mu[r];
        rs[r] = rsqrtf(var + EPS);
      }
      const int c8 = (rowbase >> 2) + fm * 4 + q;  // u64 chunk of token group
#pragma unroll
      for (int fn = 0; fn < 4; ++fn) {
        int d = fn * 16 + m;
        u64 pk = 0;
#pragma unroll
        for (int r = 0; r < 4; ++r) {
          u16 hv = f2bf((acc[fm][h2 * 4 + fn][r] - mu[r]) * rs[r]);
          pk |= (u64)hv << (16 * r);
        }
        int slot8 = (((c8 >> 1) ^ (d & 15)) << 1) | (c8 & 1);
        *(u64*)(matb + d * 128 + slot8 * 4) = pk;
      }
    }
  }
  __syncthreads();

  // dots[d][e] += kn^T over 128 tokens, per head
  const int b = blockIdx.x >> 6;
#pragma unroll
  for (int h2 = 0; h2 < 2; ++h2) {
    const u16* kn = smem + h2 * 16384;
    const u16* vn = kn + 8192;
    f32x4 dacc[4];
#pragma unroll
    for (int f = 0; f < 4; ++f) dacc[f] = (f32x4){0.f, 0.f, 0.f, 0.f};
#pragma unroll
    for (int ks = 0; ks < 4; ++ks) {
      int c16 = ks * 4 + q;
      int da = wave * 16 + m;
      bf16x8 a = *(const bf16x8*)&kn[da * 128 + ((c16 ^ (da & 15)) * 8)];
#pragma unroll
      for (int fn = 0; fn < 4; ++fn) {
        int e = fn * 16 + m;
        bf16x8 bb = *(const bf16x8*)&vn[e * 128 + ((c16 ^ (e & 15)) * 8)];
        dacc[fn] = __builtin_amdgcn_mfma_f32_16x16x32_bf16(a, bb, dacc[fn], 0, 0, 0);
      }
    }
    float* dbase = dots + (size_t)(b * 8 + hp * 2 + h2) * 4096;
#pragma unroll
    for (int fn = 0; fn < 4; ++fn) {
      int e = fn * 16 + m;
#pragma unroll
      for (int r = 0; r < 4; ++r) {
        int d = wave * 16 + q * 4 + r;
        atomicAdd(dbase + d * 64 + e, dacc[fn][r]);
      }
    }
  }
}

// ---------------- fold dots into w_out (unchanged) ----------------
__global__ __launch_bounds__(256) void make_M(const float* __restrict__ dots,
                                              const float* __restrict__ wout,
                                              u16* __restrict__ Mbt) {
  __shared__ float dl[8][64];
  const int bh = blockIdx.x, b = bh >> 3, h = bh & 7;
  const int jg = blockIdx.y;
  const int c = threadIdx.x;
  for (int i = threadIdx.x; i < 512; i += 256)
    ((float*)dl)[i] = dots[(size_t)bh * 4096 + jg * 512 + i];
  __syncthreads();
  float accv[8];
#pragma unroll
  for (int jj = 0; jj < 8; ++jj) accv[jj] = 0.f;
  for (int e = 0; e < 64; ++e) {
    float w = wout[(h * 64 + e) * DIM + c];
#pragma unroll
    for (int jj = 0; jj < 8; ++jj) accv[jj] = fmaf(dl[jj][e], w, accv[jj]);
  }
  const float inv_n = 1.0f / (float)SEQ;
  u16* outp = Mbt + ((size_t)(b * 256 + c)) * 512 + h * 64 + jg * 8;
#pragma unroll
  for (int jj = 0; jj < 8; ++jj) outp[jj] = f2bf(accv[jj] * inv_n);
}

// ---------------- make_G (unchanged): Gt[b][c][k] = sum_j Mbt[b][c][j]*wqB[k][j] ----
__global__ __launch_bounds__(256) void make_G(const u16* __restrict__ Mbt,
                                              const u16* __restrict__ wqB,
                                              u16* __restrict__ Gt) {
  __shared__ alignas(16) u16 sA[128 * 64];
  __shared__ alignas(16) u16 sB[128 * 64];
  const int lane = threadIdx.x & 63, wave = threadIdx.x >> 6;
  const int row0 = blockIdx.x * 128, col0 = blockIdx.y * 128;
  const int b = blockIdx.z;
  f32x4 acc[4][4];
#pragma unroll
  for (int i = 0; i < 4; ++i)
#pragma unroll
    for (int j = 0; j < 4; ++j) acc[i][j] = (f32x4){0.f, 0.f, 0.f, 0.f};

  gemm_tile(Mbt + (size_t)b * 256 * 512, INNER, wqB, INNER, INNER, row0, col0, sA, sB, acc);

  u16* out = Gt + (size_t)b * 256 * 256;
  const int mr = (wave >> 1) * 64, nc = (wave & 1) * 64;
#pragma unroll
  for (int fm = 0; fm < 4; ++fm) {
    int rbase = row0 + mr + fm * 16 + (lane >> 4) * 4;
#pragma unroll
    for (int fn = 0; fn < 4; ++fn) {
      int col = col0 + nc + fn * 16 + (lane & 15);
#pragma unroll
      for (int r = 0; r < 4; ++r)
        out[(size_t)(rbase + r) * DIM + col] = f2bf(acc[fm][fn][r]);
    }
  }
}

// ---------------- gemm_out: out = x @ G[b] + bias ----------------
// Full-K sA staging (1 barrier); B-frags gathered from row-major Gt (L2-hot
// 16B loads) — no sB, no extra barriers.
__global__ __launch_bounds__(256, 2) void gemm_out(const u16* __restrict__ A,
                                                   const u16* __restrict__ Gt,
                                                   const float* __restrict__ bias,
                                                   float* __restrict__ out) {
  __shared__ alignas(16) u16 smem[32768];  // 64 KB sA[128][256] swizzled
  const int tid = threadIdx.x, lane = tid & 63, wave = tid >> 6;
  const int m = lane & 15, q = lane >> 4;
  const int row0 = blockIdx.x * 128, col0 = blockIdx.y * 128;
  const int b = blockIdx.x >> 6;
  const u16* Bt = Gt + (size_t)b * 256 * 256;   // [256 cols][256 k]
  const int mr = (wave >> 1) * 64, nc = (wave & 1) * 64;

#pragma unroll
  for (int it = 0; it < 16; ++it) {
    int c = it * 256 + tid;
    int r = c >> 5, kc = (c ^ r) & 31;
    async16(A + (size_t)(row0 + r) * DIM + kc * 8, smem + c * 8);
  }

  f32x4 acc[4][4];
#pragma unroll
  for (int i = 0; i < 4; ++i)
#pragma unroll
    for (int j = 0; j < 4; ++j) acc[i][j] = (f32x4){0.f, 0.f, 0.f, 0.f};

  __syncthreads();

  for (int kk = 0; kk < 4; ++kk) {
#pragma unroll
    for (int ks = 0; ks < 2; ++ks) {
      bf16x8 bfr[4];
#pragma unroll
      for (int fn = 0; fn < 4; ++fn)
        bfr[fn] = *(const bf16x8*)(Bt + (size_t)(col0 + nc + fn * 16 + m) * 256 + kk * 64 + ks * 32 + q * 8);
      bf16x8 af[4];
      int g = kk * 8 + ks * 4 + q;
#pragma unroll
      for (int f = 0; f < 4; ++f) {
        int ra = mr + f * 16 + m;
        af[f] = *(const bf16x8*)&smem[ra * 256 + ((g ^ (ra & 31)) * 8)];
      }
#pragma unroll
      for (int fm = 0; fm < 4; ++fm)
#pragma unroll
        for (int fn = 0; fn < 4; ++fn)
          acc[fm][fn] = __builtin_amdgcn_mfma_f32_16x16x32_bf16(af[fm], bfr[fn], acc[fm][fn], 0, 0, 0);
    }
  }

#pragma unroll
  for (int fm = 0; fm < 4; ++fm) {
    int rbase = row0 + mr + fm * 16 + q * 4;
#pragma unroll
    for (int fn = 0; fn < 4; ++fn) {
      int col = col0 + nc + fn * 16 + m;
      float bb = bias[col];
#pragma unroll
      for (int r = 0; r < 4; ++r)
        out[(size_t)(rbase + r) * DIM + col] = acc[fm][fn][r] + bb;
    }
  }
}

// ---------------- launch ----------------
extern "C" void kernel_launch(void* const* d_in, const int* in_sizes, int n_in,
                              void* d_out, int out_size, void* d_ws, size_t ws_size,
                              hipStream_t stream) {
  const float* x     = (const float*)d_in[0];
  const float* w_qkv = (const float*)d_in[1];
  const float* w_out = (const float*)d_in[2];
  const float* b_out = (const float*)d_in[3];
  float* out = (float*)d_out;

  char* ws = (char*)d_ws;
  size_t off = 0;
  u16* xb    = (u16*)(ws + off); off += (size_t)ROWS * DIM * 2;          // 16.78 MB
  u16* wqB   = (u16*)(ws + off); off += (size_t)DIM * INNER * 2;         // 0.26 MB
  u16* wkvP  = (u16*)(ws + off); off += (size_t)HEADS * 128 * DIM * 2;   // 0.52 MB
  float* dots = (float*)(ws + off); off += (size_t)32 * 64 * 64 * 4;     // 0.52 MB
  u16* Mbt   = (u16*)(ws + off); off += (size_t)BATCH * 256 * 512 * 2;   // 1.05 MB
  u16* Gt    = (u16*)(ws + off); off += (size_t)BATCH * 256 * 256 * 2;   // 0.52 MB

  prep<<<9856, 256, 0, stream>>>(x, w_qkv, xb, wqB, wkvP, dots);
  gemm_kv_dots<<<dim3(ROWS / 128, HEADS / 2), 256, 0, stream>>>(xb, wkvP, dots);
  make_M<<<dim3(32, 8), 256, 0, stream>>>(dots, w_out, Mbt);
  make_G<<<dim3(2, 2, BATCH), 256, 0, stream>>>(Mbt, wqB, Gt);
  gemm_out<<<dim3(ROWS / 128, 2), 256, 0, stream>>>(xb, Gt, b_out, out);
}

// Round 9
// 178.946 us; speedup vs baseline: 1.0492x; 1.0492x over previous
//
#include <hip/hip_runtime.h>
#include <hip/hip_bf16.h>
#include <stdint.h>

#define HEADS 8
#define DHEAD 64
#define BATCH 4
#define SEQ   8192
#define DIM   256
#define INNER 512
#define QKVC  1536
#define ROWS  32768   // BATCH*SEQ
#define EPS   1e-5f

typedef unsigned short u16;
typedef unsigned long long u64;
typedef __attribute__((ext_vector_type(8))) short bf16x8;
typedef __attribute__((ext_vector_type(4))) float f32x4;

#define AS1 __attribute__((address_space(1)))
#define AS3 __attribute__((address_space(3)))

__device__ __forceinline__ void async16(const void* g, void* l) {
  __builtin_amdgcn_global_load_lds((AS1 unsigned int*)g, (AS3 unsigned int*)l, 16, 0, 0);
}

__device__ __forceinline__ float bf2f(u16 u) {
  union { uint32_t i; float f; } v; v.i = ((uint32_t)u) << 16; return v.f;
}
__device__ __forceinline__ u16 f2bf(float f) {
  union { float f; uint32_t i; } v; v.f = f;
  uint32_t x = v.i;
  return (u16)((x + 0x7fffu + ((x >> 16) & 1u)) >> 16);  // RNE
}

// ---------------- prep (unchanged) ----------------
__global__ __launch_bounds__(256) void prep(const float* __restrict__ x,
                                            const float* __restrict__ w,
                                            u16* __restrict__ xb,
                                            u16* __restrict__ wqB,
                                            u16* __restrict__ wkvP,
                                            float* __restrict__ dots) {
  int bid = blockIdx.x;
  if (bid < 8192) {
    int i = (bid * 256 + threadIdx.x) * 4;
    float4 v = *(const float4*)(x + i);
    ushort4 o; o.x = f2bf(v.x); o.y = f2bf(v.y); o.z = f2bf(v.z); o.w = f2bf(v.w);
    *(ushort4*)(xb + i) = o;
  } else if (bid < 8704) {
    int id = (bid - 8192) * 256 + threadIdx.x;
    int k = id >> 9, j = id & 511;
    wqB[id] = f2bf(w[k * QKVC + j]);            // Wq row-major [256 k][512 j]
  } else if (bid < 9728) {
    int id = (bid - 8704) * 256 + threadIdx.x;  // 0..262143
    int j    = id & 7;
    int lane = (id >> 3) & 63;
    int frag = (id >> 9) & 63;                  // 64 fragments
    int h    = id >> 15;                        // 8 heads
    int fn   = frag & 3;
    int half = (frag >> 2) & 1;
    int ks   = (frag >> 3) & 1;
    int kk   = frag >> 4;
    int col  = half * 64 + fn * 16 + (lane & 15);
    int kidx = kk * 64 + ks * 32 + (lane >> 4) * 8 + j;
    int oc   = (col < 64) ? (512 + h * 64 + col) : (1024 + h * 64 + (col - 64));
    wkvP[id] = f2bf(w[kidx * QKVC + oc]);
  } else {
    int i = ((bid - 9728) * 256 + threadIdx.x) * 4;
    float4 z; z.x = 0.f; z.y = 0.f; z.z = 0.f; z.w = 0.f;
    *(float4*)(dots + i) = z;
  }
}

// ---------------- gemm_tile (used by make_G only) ----------------
__device__ __forceinline__ void gemm_tile(const u16* __restrict__ A, int lda,
                                          const u16* __restrict__ Bt, int ldb,
                                          int K, int row0, int col0,
                                          u16* sA, u16* sB, f32x4 acc[4][4]) {
  const int tid = threadIdx.x, lane = tid & 63, wave = tid >> 6;
  const int m = lane & 15, q = lane >> 4;
  const int mr = (wave >> 1) * 64, nc = (wave & 1) * 64;
  for (int kk = 0; kk < K; kk += 64) {
#pragma unroll
    for (int it = 0; it < 4; ++it) {
      int c = it * 256 + tid;
      int r = c >> 3, kc = (c ^ r) & 7;
      async16(A + (size_t)(row0 + r) * lda + kk + kc * 8, sA + (it * 256 + wave * 64) * 8);
      async16(Bt + (size_t)(col0 + r) * ldb + kk + kc * 8, sB + (it * 256 + wave * 64) * 8);
    }
    __syncthreads();
#pragma unroll
    for (int ks = 0; ks < 2; ++ks) {
      bf16x8 af[4], bfr[4];
#pragma unroll
      for (int f = 0; f < 4; ++f) {
        int ra = mr + f * 16 + m;
        int rb = nc + f * 16 + m;
        af[f]  = *(const bf16x8*)&sA[ra * 64 + (((ks * 4 + q) ^ (m & 7)) * 8)];
        bfr[f] = *(const bf16x8*)&sB[rb * 64 + (((ks * 4 + q) ^ (m & 7)) * 8)];
      }
#pragma unroll
      for (int fm = 0; fm < 4; ++fm)
#pragma unroll
        for (int fn = 0; fn < 4; ++fn)
          acc[fm][fn] = __builtin_amdgcn_mfma_f32_16x16x32_bf16(af[fm], bfr[fn], acc[fm][fn], 0, 0, 0);
    }
    __syncthreads();
  }
}

// ---------------- GEMM-KV + instance norm + dots (R7 structure, 4 tiles/block) ----
// grid (64 row-groups of 512 tokens, 8 heads) = 512 blocks. dacc accumulates in
// registers across 4 row-tiles; ONE atomic flush per block -> 2.1M atomics
// (was 8.4M / 32.7 MB write-through). Everything else identical to R7's proven
// 50.5 us kernel (sA swizzled, B register-resident, 34.8 KB LDS).
__global__ __launch_bounds__(256, 2) void gemm_kv_dots(const u16* __restrict__ A,
                                                       const u16* __restrict__ wkvP,
                                                       float* __restrict__ dots) {
  __shared__ alignas(16) u16 smem[17408];  // 34816 B
  u16* sA  = smem;            // [128 rows][64] swizzled, K-loop only
  u16* knT = smem;            // [64 d][136 tok] — aliases sA post K-loop
  u16* vnT = smem + 8704;

  const int tid = threadIdx.x, lane = tid & 63, wave = tid >> 6;
  const int m = lane & 15, q = lane >> 4;
  const int h = blockIdx.y;
  const int half = wave & 1;              // 0 = k cols, 1 = v cols
  const int rowbase = (wave >> 1) * 64;
  const u16* bp = wkvP + (size_t)h * 32768 + lane * 8;

  f32x4 dacc[4];
#pragma unroll
  for (int f = 0; f < 4; ++f) dacc[f] = (f32x4){0.f, 0.f, 0.f, 0.f};

  for (int t = 0; t < 4; ++t) {
    const int row0 = (blockIdx.x * 4 + t) * 128;

    f32x4 acc[4][4];
#pragma unroll
    for (int i = 0; i < 4; ++i)
#pragma unroll
      for (int j = 0; j < 4; ++j) acc[i][j] = (f32x4){0.f, 0.f, 0.f, 0.f};

#pragma unroll
    for (int kk = 0; kk < 4; ++kk) {
      // B fragments: coalesced 16B L2-hot loads, drained by the same barrier
      bf16x8 breg[2][4];
#pragma unroll
      for (int ks = 0; ks < 2; ++ks)
#pragma unroll
        for (int fn = 0; fn < 4; ++fn)
          breg[ks][fn] = *(const bf16x8*)(bp + (size_t)((((kk * 2 + ks) * 2 + half) * 4 + fn) * 512));
      // stage sA (swizzled)
#pragma unroll
      for (int it = 0; it < 4; ++it) {
        int c = it * 256 + tid;
        int r = c >> 3, kc = (c ^ r) & 7;
        async16(A + (size_t)(row0 + r) * DIM + kk * 64 + kc * 8, sA + (it * 256 + wave * 64) * 8);
      }
      __syncthreads();
#pragma unroll
      for (int ks = 0; ks < 2; ++ks) {
        bf16x8 af[4];
#pragma unroll
        for (int f = 0; f < 4; ++f) {
          int r = rowbase + f * 16 + m;
          af[f] = *(const bf16x8*)&sA[r * 64 + (((ks * 4 + q) ^ (m & 7)) * 8)];
        }
#pragma unroll
        for (int fm = 0; fm < 4; ++fm)
#pragma unroll
          for (int fn = 0; fn < 4; ++fn)
            acc[fm][fn] = __builtin_amdgcn_mfma_f32_16x16x32_bf16(af[fm], breg[ks][fn], acc[fm][fn], 0, 0, 0);
      }
      __syncthreads();
    }

    // instance norm: shfl butterfly over lane&15, write transposed bf16
    u16* dst = half ? vnT : knT;
#pragma unroll
    for (int fm = 0; fm < 4; ++fm) {
      f32x4 s  = acc[fm][0] + acc[fm][1] + acc[fm][2] + acc[fm][3];
      f32x4 s2 = (f32x4){0.f, 0.f, 0.f, 0.f};
#pragma unroll
      for (int fn = 0; fn < 4; ++fn)
#pragma unroll
        for (int r = 0; r < 4; ++r) s2[r] = fmaf(acc[fm][fn][r], acc[fm][fn][r], s2[r]);
#pragma unroll
      for (int mask = 1; mask <= 8; mask <<= 1) {
#pragma unroll
        for (int r = 0; r < 4; ++r) {
          s[r]  += __shfl_xor(s[r],  mask, 64);
          s2[r] += __shfl_xor(s2[r], mask, 64);
        }
      }
      f32x4 mu, rs;
#pragma unroll
      for (int r = 0; r < 4; ++r) {
        mu[r] = s[r] * (1.f / 64.f);
        float var = s2[r] * (1.f / 64.f) - mu[r] * mu[r];
        rs[r] = rsqrtf(var + EPS);
      }
      const int tokb = rowbase + fm * 16 + q * 4;
#pragma unroll
      for (int fn = 0; fn < 4; ++fn) {
        int d = fn * 16 + m;
        u64 pk = 0;
#pragma unroll
        for (int r = 0; r < 4; ++r) {
          u16 hv = f2bf((acc[fm][fn][r] - mu[r]) * rs[r]);
          pk |= (u64)hv << (16 * r);
        }
        *(u64*)(dst + d * 136 + tokb) = pk;   // 8B-aligned; 2-way bank alias (free)
      }
    }
    __syncthreads();

    // dots accumulate: dacc[d][e] += sum_tok knT[d][tok]*vnT[e][tok] (K=128)
#pragma unroll
    for (int ks = 0; ks < 4; ++ks) {
      bf16x8 a = *(const bf16x8*)&knT[(wave * 16 + m) * 136 + ks * 32 + q * 8];
#pragma unroll
      for (int fn = 0; fn < 4; ++fn) {
        bf16x8 bb = *(const bf16x8*)&vnT[(fn * 16 + m) * 136 + ks * 32 + q * 8];
        dacc[fn] = __builtin_amdgcn_mfma_f32_16x16x32_bf16(a, bb, dacc[fn], 0, 0, 0);
      }
    }
    __syncthreads();  // protect knT/vnT (alias sA) before next tile's staging
  }

  const int b = blockIdx.x >> 4;  // 16 row-groups per batch (64 groups / 4 batches)
  float* dbase = dots + (size_t)(b * 8 + h) * 4096;
#pragma unroll
  for (int fn = 0; fn < 4; ++fn) {
    int e = fn * 16 + m;
#pragma unroll
    for (int r = 0; r < 4; ++r) {
      int d = wave * 16 + q * 4 + r;
      atomicAdd(dbase + d * 64 + e, dacc[fn][r]);
    }
  }
}

// ---------------- fold dots into w_out (unchanged) ----------------
__global__ __launch_bounds__(256) void make_M(const float* __restrict__ dots,
                                              const float* __restrict__ wout,
                                              u16* __restrict__ Mbt) {
  __shared__ float dl[8][64];
  const int bh = blockIdx.x, b = bh >> 3, h = bh & 7;
  const int jg = blockIdx.y;
  const int c = threadIdx.x;
  for (int i = threadIdx.x; i < 512; i += 256)
    ((float*)dl)[i] = dots[(size_t)bh * 4096 + jg * 512 + i];
  __syncthreads();
  float accv[8];
#pragma unroll
  for (int jj = 0; jj < 8; ++jj) accv[jj] = 0.f;
  for (int e = 0; e < 64; ++e) {
    float w = wout[(h * 64 + e) * DIM + c];
#pragma unroll
    for (int jj = 0; jj < 8; ++jj) accv[jj] = fmaf(dl[jj][e], w, accv[jj]);
  }
  const float inv_n = 1.0f / (float)SEQ;
  u16* outp = Mbt + ((size_t)(b * 256 + c)) * 512 + h * 64 + jg * 8;
#pragma unroll
  for (int jj = 0; jj < 8; ++jj) outp[jj] = f2bf(accv[jj] * inv_n);
}

// ---------------- make_G (unchanged): Gt[b][c][k] = sum_j Mbt[b][c][j]*wqB[k][j] ----
__global__ __launch_bounds__(256) void make_G(const u16* __restrict__ Mbt,
                                              const u16* __restrict__ wqB,
                                              u16* __restrict__ Gt) {
  __shared__ alignas(16) u16 sA[128 * 64];
  __shared__ alignas(16) u16 sB[128 * 64];
  const int lane = threadIdx.x & 63, wave = threadIdx.x >> 6;
  const int row0 = blockIdx.x * 128, col0 = blockIdx.y * 128;
  const int b = blockIdx.z;
  f32x4 acc[4][4];
#pragma unroll
  for (int i = 0; i < 4; ++i)
#pragma unroll
    for (int j = 0; j < 4; ++j) acc[i][j] = (f32x4){0.f, 0.f, 0.f, 0.f};

  gemm_tile(Mbt + (size_t)b * 256 * 512, INNER, wqB, INNER, INNER, row0, col0, sA, sB, acc);

  u16* out = Gt + (size_t)b * 256 * 256;
  const int mr = (wave >> 1) * 64, nc = (wave & 1) * 64;
#pragma unroll
  for (int fm = 0; fm < 4; ++fm) {
    int rbase = row0 + mr + fm * 16 + (lane >> 4) * 4;
#pragma unroll
    for (int fn = 0; fn < 4; ++fn) {
      int col = col0 + nc + fn * 16 + (lane & 15);
#pragma unroll
      for (int r = 0; r < 4; ++r)
        out[(size_t)(rbase + r) * DIM + col] = f2bf(acc[fm][fn][r]);
    }
  }
}

// ---------------- gemm_out (R8 version — kept): out = x @ G[b] + bias ----------------
__global__ __launch_bounds__(256, 2) void gemm_out(const u16* __restrict__ A,
                                                   const u16* __restrict__ Gt,
                                                   const float* __restrict__ bias,
                                                   float* __restrict__ out) {
  __shared__ alignas(16) u16 smem[32768];  // 64 KB sA[128][256] swizzled
  const int tid = threadIdx.x, lane = tid & 63, wave = tid >> 6;
  const int m = lane & 15, q = lane >> 4;
  const int row0 = blockIdx.x * 128, col0 = blockIdx.y * 128;
  const int b = blockIdx.x >> 6;
  const u16* Bt = Gt + (size_t)b * 256 * 256;   // [256 cols][256 k]
  const int mr = (wave >> 1) * 64, nc = (wave & 1) * 64;

#pragma unroll
  for (int it = 0; it < 16; ++it) {
    int c = it * 256 + tid;
    int r = c >> 5, kc = (c ^ r) & 31;
    async16(A + (size_t)(row0 + r) * DIM + kc * 8, smem + c * 8);
  }

  f32x4 acc[4][4];
#pragma unroll
  for (int i = 0; i < 4; ++i)
#pragma unroll
    for (int j = 0; j < 4; ++j) acc[i][j] = (f32x4){0.f, 0.f, 0.f, 0.f};

  __syncthreads();

  for (int kk = 0; kk < 4; ++kk) {
#pragma unroll
    for (int ks = 0; ks < 2; ++ks) {
      bf16x8 bfr[4];
#pragma unroll
      for (int fn = 0; fn < 4; ++fn)
        bfr[fn] = *(const bf16x8*)(Bt + (size_t)(col0 + nc + fn * 16 + m) * 256 + kk * 64 + ks * 32 + q * 8);
      bf16x8 af[4];
      int g = kk * 8 + ks * 4 + q;
#pragma unroll
      for (int f = 0; f < 4; ++f) {
        int ra = mr + f * 16 + m;
        af[f] = *(const bf16x8*)&smem[ra * 256 + ((g ^ (ra & 31)) * 8)];
      }
#pragma unroll
      for (int fm = 0; fm < 4; ++fm)
#pragma unroll
        for (int fn = 0; fn < 4; ++fn)
          acc[fm][fn] = __builtin_amdgcn_mfma_f32_16x16x32_bf16(af[fm], bfr[fn], acc[fm][fn], 0, 0, 0);
    }
  }

#pragma unroll
  for (int fm = 0; fm < 4; ++fm) {
    int rbase = row0 + mr + fm * 16 + q * 4;
#pragma unroll
    for (int fn = 0; fn < 4; ++fn) {
      int col = col0 + nc + fn * 16 + m;
      float bb = bias[col];
#pragma unroll
      for (int r = 0; r < 4; ++r)
        out[(size_t)(rbase + r) * DIM + col] = acc[fm][fn][r] + bb;
    }
  }
}

// ---------------- launch ----------------
extern "C" void kernel_launch(void* const* d_in, const int* in_sizes, int n_in,
                              void* d_out, int out_size, void* d_ws, size_t ws_size,
                              hipStream_t stream) {
  const float* x     = (const float*)d_in[0];
  const float* w_qkv = (const float*)d_in[1];
  const float* w_out = (const float*)d_in[2];
  const float* b_out = (const float*)d_in[3];
  float* out = (float*)d_out;

  char* ws = (char*)d_ws;
  size_t off = 0;
  u16* xb    = (u16*)(ws + off); off += (size_t)ROWS * DIM * 2;          // 16.78 MB
  u16* wqB   = (u16*)(ws + off); off += (size_t)DIM * INNER * 2;         // 0.26 MB
  u16* wkvP  = (u16*)(ws + off); off += (size_t)HEADS * 128 * DIM * 2;   // 0.52 MB
  float* dots = (float*)(ws + off); off += (size_t)32 * 64 * 64 * 4;     // 0.52 MB
  u16* Mbt   = (u16*)(ws + off); off += (size_t)BATCH * 256 * 512 * 2;   // 1.05 MB
  u16* Gt    = (u16*)(ws + off); off += (size_t)BATCH * 256 * 256 * 2;   // 0.52 MB

  prep<<<9856, 256, 0, stream>>>(x, w_qkv, xb, wqB, wkvP, dots);
  gemm_kv_dots<<<dim3(ROWS / 512, HEADS), 256, 0, stream>>>(xb, wkvP, dots);
  make_M<<<dim3(32, 8), 256, 0, stream>>>(dots, w_out, Mbt);
  make_G<<<dim3(2, 2, BATCH), 256, 0, stream>>>(Mbt, wqB, Gt);
  gemm_out<<<dim3(ROWS / 128, 2), 256, 0, stream>>>(xb, Gt, b_out, out);
}